// Round 12
// baseline (202.188 us; speedup 1.0000x reference)
//
#include <hip/hip_runtime.h>

// Problem constants
#define NN   768
#define KKN  32
#define CS   384
#define CZ   128
#define CG   16
#define NH   4
#define DHD  32
#define NRBF 64
#define EE   (NN*KKN)

#define RBF_STEP    (20.0f/63.0f)
#define RBF_INVSTEP (63.0f/20.0f)
#define RBF_INVSIG  3.2f            // 1/0.3125
#define RBF_SI      (RBF_STEP*RBF_INVSIG)

typedef __attribute__((ext_vector_type(8))) short bf16x8;
typedef __attribute__((ext_vector_type(4))) float f32x4;

// ---------- helpers ----------
__device__ __forceinline__ float bfl(unsigned int u){ return __uint_as_float(u << 16); }
__device__ __forceinline__ float bfh(unsigned int u){ return __uint_as_float(u & 0xFFFF0000u); }
// HW packed f32->bf16 RNE conversion: 1 VALU op
__device__ __forceinline__ unsigned int packbf(float a, float b){
  unsigned int r;
  asm("v_cvt_pk_bf16_f32 %0, %1, %2" : "=v"(r) : "v"(a), "v"(b));
  return r;
}
// raw v_rcp_f32 (~1 ulp) — avoids the IEEE div sequence
__device__ __forceinline__ float fastrcp(float x){
  float r;
  asm("v_rcp_f32 %0, %1" : "=v"(r) : "v"(x));
  return r;
}
__device__ __forceinline__ float sigm(float x){ return fastrcp(1.0f + __expf(-x)); }

// ---------- K1: LN + nl/nr GEMM (K-split x8) + merged one-time weight packing ----------
__global__ __launch_bounds__(256) void k1_pre(
    const float* __restrict__ nf, const float* __restrict__ ef,
    const float* __restrict__ wl, const float* __restrict__ bl,
    const float* __restrict__ wr, const float* __restrict__ br,
    const float* __restrict__ lng, const float* __restrict__ lnb,
    float* __restrict__ nlw, float* __restrict__ nrw,
    unsigned short* __restrict__ zw,
    const float* __restrict__ wq, const float* __restrict__ wkv,
    const float* __restrict__ wog, const float* __restrict__ wout,
    const float* __restrict__ wd, const float* __restrict__ wt,
    const float* __restrict__ wb, const float* __restrict__ bgf,
    unsigned short* __restrict__ wqkvogT, unsigned short* __restrict__ woutT,
    unsigned short* __restrict__ wdT, unsigned short* __restrict__ wtT,
    unsigned short* __restrict__ wbP, unsigned short* __restrict__ bgP)
{
  int b = blockIdx.x, t = threadIdx.x;
  if (b < 1536){
    int rl = t >> 4, l16 = t & 15;
    size_t e = (size_t)b*16 + rl;
    const float4* row = (const float4*)(ef + e*CZ);
    float4 x0 = row[l16*2], x1 = row[l16*2+1];
    float v[8] = {x0.x,x0.y,x0.z,x0.w,x1.x,x1.y,x1.z,x1.w};
    float s = 0.f, q = 0.f;
    #pragma unroll
    for (int u=0;u<8;u++){ s += v[u]; q += v[u]*v[u]; }
    #pragma unroll
    for (int m=1;m<16;m<<=1){ s += __shfl_xor(s,m); q += __shfl_xor(q,m); }
    float mean = s*(1.f/128.f);
    float var  = q*(1.f/128.f) - mean*mean;
    float rs = rsqrtf(var + 1e-5f);
    int c0 = l16*8;
    unsigned int pk[4];
    #pragma unroll
    for (int u=0;u<4;u++){
      float z0 = (v[2*u]  -mean)*rs*lng[c0+2*u]   + lnb[c0+2*u];
      float z1 = (v[2*u+1]-mean)*rs*lng[c0+2*u+1] + lnb[c0+2*u+1];
      pk[u] = packbf(z0,z1);
    }
    ((uint4*)(zw + e*CZ))[l16] = make_uint4(pk[0],pk[1],pk[2],pk[3]);
  } else if (b < 2304){
    int blk2 = b - 1536;           // 0..767
    int seg = blk2 / 96;           // 0..7
    int within = blk2 - seg*96;
    int gid = within*256 + t;      // 0..24575
    int side = (gid >= 12288) ? 1 : 0;
    int idx = gid - side*12288;
    int nd = idx >> 4, c = idx & 15;
    const float* w = side ? wr : wl;
    float acc = (seg==0) ? (side ? br[c] : bl[c]) : 0.f;
    const float* nrow = nf + (size_t)nd*CS;
    int kb = seg*48;
    #pragma unroll 4
    for (int k=kb;k<kb+48;k++) acc += nrow[k]*w[k*CG+c];
    atomicAdd((side? nrw : nlw)+idx, acc);
  } else {
    // ---- former k0_prep (weight transpose/pack), ids 0..15683 ----
    int id = (b - 2304)*256 + t;
    float v[8];
    if (id < 8192){
      int c = id & 511, g = id >> 9;
      const float* src; int ld, col;
      if (c < 128){ src = wq; ld = 128; col = c; }
      else if (c < 384){ src = wkv; ld = 256; col = c-128; }
      else { src = wog; ld = 128; col = c-384; }
      #pragma unroll
      for (int j=0;j<8;j++) v[j] = src[(size_t)(g*8+j)*ld + col];
      *(uint4*)(wqkvogT + c*128 + ((g + c)&15)*8) = make_uint4(
        packbf(v[0],v[1]),packbf(v[2],v[3]),packbf(v[4],v[5]),packbf(v[6],v[7]));
    } else if (id < 10240){
      int l = id - 8192; int c = l & 127, g = l >> 7;
      #pragma unroll
      for (int j=0;j<8;j++) v[j] = wout[(size_t)(g*8+j)*128 + c];
      *(uint4*)(woutT + c*128 + ((g + c)&15)*8) = make_uint4(
        packbf(v[0],v[1]),packbf(v[2],v[3]),packbf(v[4],v[5]),packbf(v[6],v[7]));
    } else if (id < 11392){
      int l = id - 10240; int c = l & 127, g = l >> 7;   // g 0..8
      #pragma unroll
      for (int j=0;j<8;j++) v[j] = (g<8) ? wd[(size_t)(g*8+j)*128 + c] : 0.f;
      *(uint4*)(wdT + c*72 + g*8) = make_uint4(
        packbf(v[0],v[1]),packbf(v[2],v[3]),packbf(v[4],v[5]),packbf(v[6],v[7]));
    } else if (id < 11460){
      int l = id - 11392; int h = l / 17, g = l % 17;
      #pragma unroll
      for (int j=0;j<8;j++){ int cc = g*8+j; v[j] = (cc<128)? wt[cc*4 + h] : 0.f; }
      *(uint4*)(wtT + h*136 + g*8) = make_uint4(
        packbf(v[0],v[1]),packbf(v[2],v[3]),packbf(v[4],v[5]),packbf(v[6],v[7]));
    } else if (id < 15556){
      int l2 = id - 11460;           // 0..4095
      int c = l2 >> 5, sl = l2 & 31; // c 0..127, sl 0..31
      int kl0 = sl*8;
      #pragma unroll
      for (int j=0;j<8;j++) v[j] = wb[(size_t)(kl0+j)*128 + c];
      *(uint4*)(wbP + c*256 + kl0) = make_uint4(
        packbf(v[0],v[1]),packbf(v[2],v[3]),packbf(v[4],v[5]),packbf(v[6],v[7]));
    } else if (id < 15684){
      // bgP[c][0..7] = {bf16(bg[c]), 0...} — the k=16 MFMA slot folding bg into ga
      int c = id - 15556;
      *(uint4*)(bgP + c*8) = make_uint4(packbf(bgf[c], 0.f), 0u, 0u, 0u);
    }
  }
}

// ---------- K1b: S_all[s][c*16+l] = nl[s] . wb   (768 blocks) + nr bf16 pack ----------
__global__ __launch_bounds__(256) void k1b_sprep(
    const float* __restrict__ nlw, const float* __restrict__ nrw,
    const unsigned short* __restrict__ wbP,
    unsigned short* __restrict__ S_all, unsigned short* __restrict__ nrb)
{
  int n = blockIdx.x, t = threadIdx.x;
  float e1[16];
  #pragma unroll
  for (int k=0;k<16;k++) e1[k] = nlw[n*CG + k];
  int c = t>>1, l0 = (t&1)*8;
  float S[8];
  #pragma unroll
  for (int u=0;u<8;u++) S[u]=0.f;
  const unsigned short* wrow = wbP + c*256 + l0;
  #pragma unroll 4
  for (int k=0;k<16;k++){
    uint4 wv = *(const uint4*)(wrow + k*16);
    float wf[8] = { bfl(wv.x), bfh(wv.x), bfl(wv.y), bfh(wv.y),
                    bfl(wv.z), bfh(wv.z), bfl(wv.w), bfh(wv.w) };
    float ev = e1[k];
    #pragma unroll
    for (int u=0;u<8;u++) S[u] = fmaf(ev, wf[u], S[u]);
  }
  *(uint4*)(S_all + (size_t)n*2048 + c*16 + l0) = make_uint4(
    packbf(S[0],S[1]), packbf(S[2],S[3]), packbf(S[4],S[5]), packbf(S[6],S[7]));
  if (t < 8){
    *(unsigned int*)(nrb + n*CG + 2*t) = packbf(nrw[n*CG + 2*t], nrw[n*CG + 2*t + 1]);
  }
}

// ---------- K2 (MFMA): bias[n][h][i][j] per (node, 4-i chunk) ----------
// LAUNCH-BOUNDS LEDGER (hard-won):
//   (256,4) cap128 -> 56-64 VGPR, no spill, PASSES.  [R0/R1/R6/R7: 63-67us]
//   (256,6) cap80  -> 40 VGPR + 34KB/block scratch spill, 122us. [R4]
//   (256,8) cap64  -> numerical corruption absmax~0.11, 2-for-2. [R2,R5]
// STRUCTURE LEDGER:
//   dbuf + deferred-final (R8) -> partial spill (WRITE 26->44MB), 70us. REVERTED.
//   rolling aS prefetch (R7)   -> 63.0us, neutral-positive. KEPT.
// k2 is at its structural floor (~63us) for this decomposition.
__global__ __launch_bounds__(256,4) void k2_bias(
    const long long* __restrict__ eidx, const float* __restrict__ trans,
    const unsigned short* __restrict__ S_all, const unsigned short* __restrict__ nrb,
    const unsigned short* __restrict__ wdTg, const unsigned short* __restrict__ wtTg,
    const unsigned short* __restrict__ bgP, const float* __restrict__ bd,
    float* __restrict__ biasw)
{
  int n = blockIdx.x >> 3, chunk = blockIdx.x & 7;
  int i0 = chunk*4;
  int t = threadIdx.x;
  int wave = t>>6, lane = t&63, q = lane>>4, l15 = lane&15;

  __shared__ __align__(16) unsigned short rbfb[32*72];   // 4.5 KB  [j][r]
  __shared__ __align__(16) unsigned short Xb  [32*136];  // 8.5 KB  [j][c]
  __shared__ __align__(16) float t3s[32][4];
  __shared__ __align__(16) float dsm[4][32];
  __shared__ int srcs[32];

  f32x4 zero4 = {0.f,0.f,0.f,0.f};
  uint4 uz = make_uint4(0,0,0,0);

  // ph0: srcs
  if (t < 32) srcs[t] = (int)eidx[(size_t)n*KKN + t];
  __syncthreads();
  // ph1: t3s gather + per-lane invariant fragments
  if (t < 32){ int s = srcs[t];
    t3s[t][0]=trans[s*3]; t3s[t][1]=trans[s*3+1]; t3s[t][2]=trans[s*3+2]; }
  uint4 wdf[2][2];
  #pragma unroll
  for (int mt=0;mt<2;mt++){
    #pragma unroll
    for (int ks=0;ks<2;ks++)
      wdf[mt][ks] = *(const uint4*)(wdTg + (wave*32+mt*16+l15)*72 + ks*32 + q*8);
  }
  uint4 wtf[4];
  #pragma unroll
  for (int ks=0;ks<4;ks++)
    wtf[ks] = *(const uint4*)(wtTg + (l15&3)*136 + ks*32 + q*8);
  uint4 aBias[2];
  #pragma unroll
  for (int mt=0;mt<2;mt++)
    aBias[mt] = (q == 2) ? *(const uint4*)(bgP + (wave*32+mt*16+l15)*8) : uz;
  uint4 bE[2];
  #pragma unroll
  for (int nt=0;nt<2;nt++){
    int jn = srcs[nt*16 + l15];
    bE[nt] = (q < 2) ? *(const uint4*)(nrb + jn*CG + q*8)
                     : (q == 2 ? make_uint4(0x3F80u,0u,0u,0u) : uz);
  }
  // aS pipeline: issue ii=0's gather now (covered by distance phase + barrier)
  uint4 aS[2], aSn[2];
  {
    int s0 = srcs[i0];
    #pragma unroll
    for (int mt=0;mt<2;mt++)
      aS[mt] = (q < 2) ? *(const uint4*)(S_all + (size_t)s0*2048 + (wave*32+mt*16+l15)*16 + q*8)
                       : aBias[mt];
  }
  __syncthreads();
  // ph2: distances
  if (t < 128){
    int ii=t>>5, j=t&31;
    float dx=t3s[i0+ii][0]-t3s[j][0]+1e-8f;
    float dy=t3s[i0+ii][1]-t3s[j][1]+1e-8f;
    float dz=t3s[i0+ii][2]-t3s[j][2]+1e-8f;
    dsm[ii][j]=sqrtf(dx*dx+dy*dy+dz*dz);
  }
  __syncthreads();

  int jr = t>>3, sl = t&7;
  int c0base = wave*32 + q*4;
  float4 bdv[2];
  #pragma unroll
  for (int mt=0;mt<2;mt++) bdv[mt] = *(const float4*)(bd + c0base + mt*16);

  #pragma unroll 1
  for (int ii=0; ii<4; ii++){
    // dense rbf fill: 8 entries/thread, one aligned b128 write
    {
      float dI = dsm[ii][jr]*RBF_INVSIG;
      float e[8];
      #pragma unroll
      for (int u=0;u<8;u++){
        float x = fmaf((float)(sl*8+u), -RBF_SI, dI);
        e[u] = __expf(-x*x);          // out-of-range terms underflow to exact 0
      }
      *(uint4*)&rbfb[jr*72 + sl*8] = make_uint4(
        packbf(e[0],e[1]), packbf(e[2],e[3]), packbf(e[4],e[5]), packbf(e[6],e[7]));
    }
    // prefetch NEXT ii's aS
    if (ii < 3){
      int s_n = srcs[i0+ii+1];
      #pragma unroll
      for (int mt=0;mt<2;mt++)
        aSn[mt] = (q < 2) ? *(const uint4*)(S_all + (size_t)s_n*2048 + (wave*32+mt*16+l15)*16 + q*8)
                          : aBias[mt];
    }
    __syncthreads();

    f32x4 ga[2][2], da[2][2];
    #pragma unroll
    for(int a=0;a<2;a++){
      #pragma unroll
      for(int b2=0;b2<2;b2++){ ga[a][b2]=zero4; da[a][b2]=zero4; }
    }
    #pragma unroll
    for(int mt=0;mt<2;mt++){
      #pragma unroll
      for(int nt=0;nt<2;nt++)
        ga[mt][nt] = __builtin_amdgcn_mfma_f32_16x16x32_bf16(
          *(const bf16x8*)&aS[mt], *(const bf16x8*)&bE[nt], ga[mt][nt], 0,0,0);
    }
    #pragma unroll
    for(int ks=0;ks<2;ks++){
      bf16x8 bR[2];
      #pragma unroll
      for(int nt=0;nt<2;nt++) bR[nt] = *(const bf16x8*)&rbfb[(nt*16+l15)*72 + ks*32 + q*8];
      #pragma unroll
      for(int mt=0;mt<2;mt++){
        #pragma unroll
        for(int nt=0;nt<2;nt++)
          da[mt][nt] = __builtin_amdgcn_mfma_f32_16x16x32_bf16(
            *(const bf16x8*)&wdf[mt][ks], bR[nt], da[mt][nt], 0,0,0);
      }
    }
    // epilogue: X[j][c] = sigmoid(ga)*(da+bd), bf16  (bg already inside ga)
    #pragma unroll
    for(int mt=0;mt<2;mt++){
      int c0 = c0base + mt*16;
      float4 bv = bdv[mt];
      #pragma unroll
      for(int nt=0;nt<2;nt++){
        float x0 = fastrcp(1.f + __expf(-ga[mt][nt][0]))*(da[mt][nt][0]+bv.x);
        float x1 = fastrcp(1.f + __expf(-ga[mt][nt][1]))*(da[mt][nt][1]+bv.y);
        float x2 = fastrcp(1.f + __expf(-ga[mt][nt][2]))*(da[mt][nt][2]+bv.z);
        float x3 = fastrcp(1.f + __expf(-ga[mt][nt][3]))*(da[mt][nt][3]+bv.w);
        *(uint2*)&Xb[(nt*16+l15)*136 + c0] = make_uint2(packbf(x0,x1), packbf(x2,x3));
      }
    }
    __syncthreads();

    // final: biasT[h][j] = wt[h][:] . X[j][:], waves 0,1 (j-halves)
    if (wave < 2){
      f32x4 bacc = {0.f,0.f,0.f,0.f};
      #pragma unroll
      for(int ks=0;ks<4;ks++){
        bf16x8 bX = *(const bf16x8*)&Xb[(wave*16+l15)*136 + ks*32 + q*8];
        bacc = __builtin_amdgcn_mfma_f32_16x16x32_bf16(*(const bf16x8*)&wtf[ks], bX, bacc, 0,0,0);
      }
      if (q==0){   // rows h=0..3 in quad-0 regs; layout [n][h][i][j]
        int j = wave*16 + l15;
        float* base = biasw + (((size_t)n*4)*32 + (i0+ii))*32 + j;
        base[0] = bacc[0]; base[1024] = bacc[1]; base[2048] = bacc[2]; base[3072] = bacc[3];
      }
    }
    aS[0] = aSn[0]; aS[1] = aSn[1];
  }
}

// ---------- K3: per-node QKV+og (MFMA) + MFMA attention + out-proj (MFMA) ----------
// Round-12: R10's counters showed OccupancyPercent 0.89% over a 138us dispatch
// => total wave residency ~10K wave-us = ~3.3us execution per wave. The kernel's
// real work is tiny; wall time was block dispatch/teardown trickle of 768
// short-lived 48KB-LDS blocks (~20 concurrent). Fix: grid 256 = 1 block/CU,
// each block loops 3 nodes (n = blockIdx + 256*it). Per-node body unchanged;
// one barrier at loop top protects Q-region reuse (slow wave's yfr reads vs
// next node's projection writes). Numerics identical.
__global__ __launch_bounds__(256,3) void k3_attn(
    const unsigned short* __restrict__ zw, const float* __restrict__ biasw,
    const unsigned short* __restrict__ wqkvogT, const unsigned short* __restrict__ woutT,
    const float* __restrict__ bq, const float* __restrict__ bkv, const float* __restrict__ bog,
    const float* __restrict__ bout, float* __restrict__ out)
{
  int t = threadIdx.x;
  int w = t>>6, lane = t&63, q = lane>>4, l15 = lane&15;

  __shared__ __align__(16) char smem[49152];
  // regions: [0,8K) Q (later y); [8K,16K) K; [16K,24K) VT[128][32]bf16;
  //          [24K,32K) og; [32K,48K) P (wave-private slices)
  f32x4 zero4 = {0.f,0.f,0.f,0.f};
  const float* bseg = (w==0)? bq : (w==1)? bkv : (w==2)? (bkv+128) : bog;

  #pragma unroll 1
  for (int n = blockIdx.x; n < NN; n += 256){
    __syncthreads();   // Q-region (y) reads of previous node complete before overwrite

    bf16x8 zfr[2][4];
    #pragma unroll
    for (int nt=0;nt<2;nt++){
      const unsigned short* zr = zw + ((size_t)n*32 + nt*16 + l15)*128;
      #pragma unroll
      for (int ks=0;ks<4;ks++) zfr[nt][ks] = *(const bf16x8*)(zr + ks*32 + q*8);
    }
    // hoisted bias loads — latency hides under projections
    const float* bb = biasw + (size_t)(n*4 + w)*1024;   // [i][j] for head w
    float bbv[2][4][2];
    #pragma unroll
    for (int mt=0;mt<2;mt++){
      #pragma unroll
      for (int rg=0;rg<4;rg++){
        int i = mt*16 + q*4 + rg;
        bbv[mt][rg][0] = bb[i*32 + l15];
        bbv[mt][rg][1] = bb[i*32 + 16 + l15];
      }
    }

    // ---- QKV+og projections: weight fragments direct from global (L2-hot) ----
    for (int r=0;r<8;r++){
      float4 bv = *(const float4*)(bseg + r*16 + q*4);
      f32x4 acc0 = zero4, acc1 = zero4;
      int cg = w*128 + r*16 + l15;
      const unsigned short* wrow = wqkvogT + cg*128;
      #pragma unroll
      for (int ks=0;ks<4;ks++){
        bf16x8 af = *(const bf16x8*)(wrow + (((ks*4+q) + cg)&15)*8);
        acc0 = __builtin_amdgcn_mfma_f32_16x16x32_bf16(af, zfr[0][ks], acc0, 0,0,0);
        acc1 = __builtin_amdgcn_mfma_f32_16x16x32_bf16(af, zfr[1][ks], acc1, 0,0,0);
      }
      #pragma unroll
      for (int nt=0;nt<2;nt++){
        f32x4 a = nt? acc1 : acc0;
        float v0,v1,v2,v3;
        if (w==3){ v0=sigm(a[0]+bv.x); v1=sigm(a[1]+bv.y); v2=sigm(a[2]+bv.z); v3=sigm(a[3]+bv.w); }
        else     { v0=a[0]+bv.x; v1=a[1]+bv.y; v2=a[2]+bv.z; v3=a[3]+bv.w; }
        int i = nt*16 + l15;
        if (w==2){
          // V transposed: VT[c][j=i], row stride 32 shorts; c = r*16+q*4+rg
          unsigned short* vt = (unsigned short*)(smem + 16384) + (r*16 + q*4)*32 + i;
          unsigned int u01 = packbf(v0,v1), u23 = packbf(v2,v3);
          vt[0]  = (unsigned short)u01;  vt[32] = (unsigned short)(u01>>16);
          vt[64] = (unsigned short)u23;  vt[96] = (unsigned short)(u23>>16);
        } else {
          int blk = ((r*2 + (q>>1)) + i) & 15;
          *(uint2*)(smem + w*8192 + i*256 + blk*16 + (q&1)*8) = make_uint2(packbf(v0,v1), packbf(v2,v3));
        }
      }
    }
    __syncthreads();

    // ---- QK^T via MFMA: wave w = head w; D[i][j] ----
    f32x4 sc4[2][2];
    {
      uint4 aQ[2], bK[2];
      #pragma unroll
      for (int mt=0;mt<2;mt++){
        int row = mt*16 + l15;
        aQ[mt] = *(const uint4*)(smem + row*256 + (((w*4+q) + row)&15)*16);
      }
      #pragma unroll
      for (int nt=0;nt<2;nt++){
        int row = nt*16 + l15;
        bK[nt] = *(const uint4*)(smem + 8192 + row*256 + (((w*4+q) + row)&15)*16);
      }
      #pragma unroll
      for (int mt=0;mt<2;mt++){
        #pragma unroll
        for (int nt=0;nt<2;nt++)
          sc4[mt][nt] = __builtin_amdgcn_mfma_f32_16x16x32_bf16(
            *(const bf16x8*)&aQ[mt], *(const bf16x8*)&bK[nt], zero4, 0,0,0);
      }
    }
    // bias + scale, then row softmax stats (rows i lane-local per (mt,rg))
    float inv_[2][4];
    #pragma unroll
    for (int mt=0;mt<2;mt++){
      #pragma unroll
      for (int rg=0;rg<4;rg++){
        sc4[mt][0][rg] = fmaf(sc4[mt][0][rg], 0.17677669529663687f, bbv[mt][rg][0]);
        sc4[mt][1][rg] = fmaf(sc4[mt][1][rg], 0.17677669529663687f, bbv[mt][rg][1]);
        float m = fmaxf(sc4[mt][0][rg], sc4[mt][1][rg]);
        m = fmaxf(m, __shfl_xor(m,1));
        m = fmaxf(m, __shfl_xor(m,2));
        m = fmaxf(m, __shfl_xor(m,4));
        m = fmaxf(m, __shfl_xor(m,8));
        sc4[mt][0][rg] = __expf(sc4[mt][0][rg] - m);
        sc4[mt][1][rg] = __expf(sc4[mt][1][rg] - m);
        float s = sc4[mt][0][rg] + sc4[mt][1][rg];
        s += __shfl_xor(s,1); s += __shfl_xor(s,2);
        s += __shfl_xor(s,4); s += __shfl_xor(s,8);
        inv_[mt][rg] = fastrcp(s);   // normalization deferred to after PV
      }
    }
    // P (unnormalized) -> wave-private slice, row-major [i][32 j] bf16
    unsigned short* Pl = (unsigned short*)(smem + 32768 + w*4096);
    #pragma unroll
    for (int mt=0;mt<2;mt++){
      #pragma unroll
      for (int nt=0;nt<2;nt++){
        unsigned int u01 = packbf(sc4[mt][nt][0], sc4[mt][nt][1]);
        unsigned int u23 = packbf(sc4[mt][nt][2], sc4[mt][nt][3]);
        unsigned short* pp = Pl + (mt*16 + q*4)*32 + nt*16 + l15;
        pp[0]  = (unsigned short)u01;  pp[32] = (unsigned short)(u01>>16);
        pp[64] = (unsigned short)u23;  pp[96] = (unsigned short)(u23>>16);
      }
    }
    __syncthreads();   // all Q-region reads complete before y overwrites it

    // ---- PV via MFMA: D2[i][dh] = P[i][:] . VT[w*32+dh][:] ----
    f32x4 ov[2][2];
    {
      uint4 aP[2], bV[2];
      #pragma unroll
      for (int mt=0;mt<2;mt++)
        aP[mt] = *(const uint4*)(Pl + (mt*16 + l15)*32 + q*8);
      #pragma unroll
      for (int nt2=0;nt2<2;nt2++)
        bV[nt2] = *(const uint4*)((unsigned short*)(smem + 16384) + (w*32 + nt2*16 + l15)*32 + q*8);
      #pragma unroll
      for (int mt=0;mt<2;mt++){
        #pragma unroll
        for (int nt2=0;nt2<2;nt2++)
          ov[mt][nt2] = __builtin_amdgcn_mfma_f32_16x16x32_bf16(
            *(const bf16x8*)&aP[mt], *(const bf16x8*)&bV[nt2], zero4, 0,0,0);
      }
    }
    // normalize + gate + write y (bf16, Q region, out-proj fragment layout)
    #pragma unroll
    for (int mt=0;mt<2;mt++){
      #pragma unroll
      for (int nt2=0;nt2<2;nt2++){
        #pragma unroll
        for (int rg=0;rg<4;rg++){
          int i = mt*16 + q*4 + rg;
          int c = w*32 + nt2*16 + l15;
          int off = i*256 + (((c>>3) + i)&15)*16 + (c&7)*2;
          unsigned short gus = *(const unsigned short*)(smem + 24576 + off);
          float g = __uint_as_float(((unsigned int)gus) << 16);
          float yv = ov[mt][nt2][rg] * inv_[mt][rg] * g;
          *(unsigned short*)(smem + off) = (unsigned short)packbf(yv, yv);
        }
      }
    }
    __syncthreads();

    // ---- out-projection: weight fragments direct from global (L2-hot) ----
    bf16x8 yfr[2][4];
    #pragma unroll
    for (int mt=0;mt<2;mt++){
      int row = mt*16 + l15;
      #pragma unroll
      for (int ks=0;ks<4;ks++)
        yfr[mt][ks] = *(const bf16x8*)(smem + row*256 + (((ks*4+q) + row)&15)*16);
    }
    #pragma unroll
    for (int r2=0;r2<2;r2++){
      int c0 = (r2*4 + w)*16;
      int cg2 = c0 + l15;
      const unsigned short* orow = woutT + cg2*128;
      f32x4 oa0 = zero4, oa1 = zero4;
      #pragma unroll
      for (int ks=0;ks<4;ks++){
        bf16x8 bf = *(const bf16x8*)(orow + (((ks*4+q) + cg2)&15)*8);
        oa0 = __builtin_amdgcn_mfma_f32_16x16x32_bf16(yfr[0][ks], bf, oa0, 0,0,0);
        oa1 = __builtin_amdgcn_mfma_f32_16x16x32_bf16(yfr[1][ks], bf, oa1, 0,0,0);
      }
      float bov = bout[cg2];
      #pragma unroll
      for (int mt=0;mt<2;mt++){
        f32x4 oa = mt? oa1 : oa0;
        #pragma unroll
        for (int rg=0; rg<4; rg++){
          int i = mt*16 + q*4 + rg;
          out[((size_t)n*32 + i)*128 + cg2] = oa[rg] + bov;
        }
      }
    }
  }
}

// ---------- launch ----------
extern "C" void kernel_launch(void* const* d_in, const int* in_sizes, int n_in,
                              void* d_out, int out_size, void* d_ws, size_t ws_size,
                              hipStream_t stream)
{
  const float* nf  = (const float*)d_in[0];
  const float* tr  = (const float*)d_in[1];
  const float* ef  = (const float*)d_in[2];
  const long long* ei = (const long long*)d_in[3];
  const float* wl  = (const float*)d_in[4];  const float* bl  = (const float*)d_in[5];
  const float* wr  = (const float*)d_in[6];  const float* br  = (const float*)d_in[7];
  const float* wbg = (const float*)d_in[8];  const float* bbg = (const float*)d_in[9];
  const float* wdi = (const float*)d_in[10]; const float* bdi = (const float*)d_in[11];
  const float* wtb = (const float*)d_in[12];
  const float* lng = (const float*)d_in[13]; const float* lnb = (const float*)d_in[14];
  const float* wq  = (const float*)d_in[15]; const float* bq  = (const float*)d_in[16];
  const float* wkv = (const float*)d_in[17]; const float* bkv = (const float*)d_in[18];
  const float* wo  = (const float*)d_in[19]; const float* bo  = (const float*)d_in[20];
  const float* wog = (const float*)d_in[21]; const float* bog = (const float*)d_in[22];
  float* outp = (float*)d_out;
  float* ws = (float*)d_ws;
  // ws layout (floats). Footprint ends at 5,598,784 floats — proven layout,
  // no growth; bgP lives in the wtTg region's slack (verified R4/R6/R7/R8/R10/R11).
  float* nlw = ws;                                            // [0, 12288)
  float* nrw = ws + 12288;                                    // [12288, 24576)
  float* biasw = ws + 24576;                                  // [24576, 3170304)  [n][h][i][j]
  unsigned short* zw      = (unsigned short*)(ws + 3170304);  // E*CZ bf16
  unsigned short* wqkvogT = (unsigned short*)(ws + 4743168);  // 32768 floats
  unsigned short* woutT   = (unsigned short*)(ws + 4775936);  // 8192 floats
  unsigned short* wdTg    = (unsigned short*)(ws + 4784128);  // 4608 floats
  unsigned short* wtTg    = (unsigned short*)(ws + 4788736);  // 1088 floats; wtT uses [0,544) shorts
  unsigned short* bgPg    = wtTg + 544;                       // wtTg slack (16B-aligned)
  unsigned short* wbPg    = (unsigned short*)(ws + 4789824);  // 16384 floats
  unsigned short* S_all   = (unsigned short*)(ws + 4806208);  // 786432 floats
  unsigned short* nrb     = (unsigned short*)(ws + 5592640);  // 6144 floats -> end 5598784

  // zero nl/nr accumulators (graph-capturable)
  hipMemsetAsync(nlw, 0, 24576*sizeof(float), stream);
  // k1 = LN (1536) + nl/nr GEMM K-split x8 (768) + weight packing (62)
  hipLaunchKernelGGL(k1_pre, dim3(2366), dim3(256), 0, stream,
                     nf, ef, wl, bl, wr, br, lng, lnb, nlw, nrw, zw,
                     wq, wkv, wog, wo, wdi, wtb, wbg, bbg,
                     wqkvogT, woutT, wdTg, wtTg, wbPg, bgPg);
  hipLaunchKernelGGL(k1b_sprep, dim3(768), dim3(256), 0, stream,
                     nlw, nrw, wbPg, S_all, nrb);
  hipLaunchKernelGGL(k2_bias, dim3(6144), dim3(256), 0, stream,
                     ei, tr, S_all, nrb, wdTg, wtTg, bgPg, bdi, biasw);
  // k3: 256 blocks (1/CU), each loops 3 nodes — fixes block-trickle
  hipLaunchKernelGGL(k3_attn, dim3(256), dim3(256), 0, stream,
                     zw, biasw, wqkvogT, woutT, bq, bkv, bog, bo, outp);
}

// Round 13
// 192.939 us; speedup vs baseline: 1.0479x; 1.0479x over previous
//
#include <hip/hip_runtime.h>

// Problem constants
#define NN   768
#define KKN  32
#define CS   384
#define CZ   128
#define CG   16
#define NH   4
#define DHD  32
#define NRBF 64
#define EE   (NN*KKN)

#define RBF_STEP    (20.0f/63.0f)
#define RBF_INVSTEP (63.0f/20.0f)
#define RBF_INVSIG  3.2f            // 1/0.3125
#define RBF_SI      (RBF_STEP*RBF_INVSIG)

typedef __attribute__((ext_vector_type(8))) short bf16x8;
typedef __attribute__((ext_vector_type(4))) float f32x4;

// ---------- helpers ----------
__device__ __forceinline__ float bfl(unsigned int u){ return __uint_as_float(u << 16); }
__device__ __forceinline__ float bfh(unsigned int u){ return __uint_as_float(u & 0xFFFF0000u); }
// HW packed f32->bf16 RNE conversion: 1 VALU op
__device__ __forceinline__ unsigned int packbf(float a, float b){
  unsigned int r;
  asm("v_cvt_pk_bf16_f32 %0, %1, %2" : "=v"(r) : "v"(a), "v"(b));
  return r;
}
// raw v_rcp_f32 (~1 ulp) — avoids the IEEE div sequence
__device__ __forceinline__ float fastrcp(float x){
  float r;
  asm("v_rcp_f32 %0, %1" : "=v"(r) : "v"(x));
  return r;
}
__device__ __forceinline__ float sigm(float x){ return fastrcp(1.0f + __expf(-x)); }

// ---------- K1: LN + nl/nr GEMM (K-split x8) + merged one-time weight packing ----------
__global__ __launch_bounds__(256) void k1_pre(
    const float* __restrict__ nf, const float* __restrict__ ef,
    const float* __restrict__ wl, const float* __restrict__ bl,
    const float* __restrict__ wr, const float* __restrict__ br,
    const float* __restrict__ lng, const float* __restrict__ lnb,
    float* __restrict__ nlw, float* __restrict__ nrw,
    unsigned short* __restrict__ zw,
    const float* __restrict__ wq, const float* __restrict__ wkv,
    const float* __restrict__ wog, const float* __restrict__ wout,
    const float* __restrict__ wd, const float* __restrict__ wt,
    const float* __restrict__ wb, const float* __restrict__ bgf,
    unsigned short* __restrict__ wqkvogT, unsigned short* __restrict__ woutT,
    unsigned short* __restrict__ wdT, unsigned short* __restrict__ wtT,
    unsigned short* __restrict__ wbP, unsigned short* __restrict__ bgP)
{
  int b = blockIdx.x, t = threadIdx.x;
  if (b < 1536){
    int rl = t >> 4, l16 = t & 15;
    size_t e = (size_t)b*16 + rl;
    const float4* row = (const float4*)(ef + e*CZ);
    float4 x0 = row[l16*2], x1 = row[l16*2+1];
    float v[8] = {x0.x,x0.y,x0.z,x0.w,x1.x,x1.y,x1.z,x1.w};
    float s = 0.f, q = 0.f;
    #pragma unroll
    for (int u=0;u<8;u++){ s += v[u]; q += v[u]*v[u]; }
    #pragma unroll
    for (int m=1;m<16;m<<=1){ s += __shfl_xor(s,m); q += __shfl_xor(q,m); }
    float mean = s*(1.f/128.f);
    float var  = q*(1.f/128.f) - mean*mean;
    float rs = rsqrtf(var + 1e-5f);
    int c0 = l16*8;
    unsigned int pk[4];
    #pragma unroll
    for (int u=0;u<4;u++){
      float z0 = (v[2*u]  -mean)*rs*lng[c0+2*u]   + lnb[c0+2*u];
      float z1 = (v[2*u+1]-mean)*rs*lng[c0+2*u+1] + lnb[c0+2*u+1];
      pk[u] = packbf(z0,z1);
    }
    ((uint4*)(zw + e*CZ))[l16] = make_uint4(pk[0],pk[1],pk[2],pk[3]);
  } else if (b < 2304){
    int blk2 = b - 1536;           // 0..767
    int seg = blk2 / 96;           // 0..7
    int within = blk2 - seg*96;
    int gid = within*256 + t;      // 0..24575
    int side = (gid >= 12288) ? 1 : 0;
    int idx = gid - side*12288;
    int nd = idx >> 4, c = idx & 15;
    const float* w = side ? wr : wl;
    float acc = (seg==0) ? (side ? br[c] : bl[c]) : 0.f;
    const float* nrow = nf + (size_t)nd*CS;
    int kb = seg*48;
    #pragma unroll 4
    for (int k=kb;k<kb+48;k++) acc += nrow[k]*w[k*CG+c];
    atomicAdd((side? nrw : nlw)+idx, acc);
  } else {
    // ---- former k0_prep (weight transpose/pack), ids 0..15683 ----
    int id = (b - 2304)*256 + t;
    float v[8];
    if (id < 8192){
      int c = id & 511, g = id >> 9;
      const float* src; int ld, col;
      if (c < 128){ src = wq; ld = 128; col = c; }
      else if (c < 384){ src = wkv; ld = 256; col = c-128; }
      else { src = wog; ld = 128; col = c-384; }
      #pragma unroll
      for (int j=0;j<8;j++) v[j] = src[(size_t)(g*8+j)*ld + col];
      *(uint4*)(wqkvogT + c*128 + ((g + c)&15)*8) = make_uint4(
        packbf(v[0],v[1]),packbf(v[2],v[3]),packbf(v[4],v[5]),packbf(v[6],v[7]));
    } else if (id < 10240){
      int l = id - 8192; int c = l & 127, g = l >> 7;
      #pragma unroll
      for (int j=0;j<8;j++) v[j] = wout[(size_t)(g*8+j)*128 + c];
      *(uint4*)(woutT + c*128 + ((g + c)&15)*8) = make_uint4(
        packbf(v[0],v[1]),packbf(v[2],v[3]),packbf(v[4],v[5]),packbf(v[6],v[7]));
    } else if (id < 11392){
      int l = id - 10240; int c = l & 127, g = l >> 7;   // g 0..8
      #pragma unroll
      for (int j=0;j<8;j++) v[j] = (g<8) ? wd[(size_t)(g*8+j)*128 + c] : 0.f;
      *(uint4*)(wdT + c*72 + g*8) = make_uint4(
        packbf(v[0],v[1]),packbf(v[2],v[3]),packbf(v[4],v[5]),packbf(v[6],v[7]));
    } else if (id < 11460){
      int l = id - 11392; int h = l / 17, g = l % 17;
      #pragma unroll
      for (int j=0;j<8;j++){ int cc = g*8+j; v[j] = (cc<128)? wt[cc*4 + h] : 0.f; }
      *(uint4*)(wtT + h*136 + g*8) = make_uint4(
        packbf(v[0],v[1]),packbf(v[2],v[3]),packbf(v[4],v[5]),packbf(v[6],v[7]));
    } else if (id < 15556){
      int l2 = id - 11460;           // 0..4095
      int c = l2 >> 5, sl = l2 & 31; // c 0..127, sl 0..31
      int kl0 = sl*8;
      #pragma unroll
      for (int j=0;j<8;j++) v[j] = wb[(size_t)(kl0+j)*128 + c];
      *(uint4*)(wbP + c*256 + kl0) = make_uint4(
        packbf(v[0],v[1]),packbf(v[2],v[3]),packbf(v[4],v[5]),packbf(v[6],v[7]));
    } else if (id < 15684){
      // bgP[c][0..7] = {bf16(bg[c]), 0...} — the k=16 MFMA slot folding bg into ga
      int c = id - 15556;
      *(uint4*)(bgP + c*8) = make_uint4(packbf(bgf[c], 0.f), 0u, 0u, 0u);
    }
  }
}

// ---------- K1b: S_all[s][c*16+l] = nl[s] . wb   (768 blocks) + nr bf16 pack ----------
__global__ __launch_bounds__(256) void k1b_sprep(
    const float* __restrict__ nlw, const float* __restrict__ nrw,
    const unsigned short* __restrict__ wbP,
    unsigned short* __restrict__ S_all, unsigned short* __restrict__ nrb)
{
  int n = blockIdx.x, t = threadIdx.x;
  float e1[16];
  #pragma unroll
  for (int k=0;k<16;k++) e1[k] = nlw[n*CG + k];
  int c = t>>1, l0 = (t&1)*8;
  float S[8];
  #pragma unroll
  for (int u=0;u<8;u++) S[u]=0.f;
  const unsigned short* wrow = wbP + c*256 + l0;
  #pragma unroll 4
  for (int k=0;k<16;k++){
    uint4 wv = *(const uint4*)(wrow + k*16);
    float wf[8] = { bfl(wv.x), bfh(wv.x), bfl(wv.y), bfh(wv.y),
                    bfl(wv.z), bfh(wv.z), bfl(wv.w), bfh(wv.w) };
    float ev = e1[k];
    #pragma unroll
    for (int u=0;u<8;u++) S[u] = fmaf(ev, wf[u], S[u]);
  }
  *(uint4*)(S_all + (size_t)n*2048 + c*16 + l0) = make_uint4(
    packbf(S[0],S[1]), packbf(S[2],S[3]), packbf(S[4],S[5]), packbf(S[6],S[7]));
  if (t < 8){
    *(unsigned int*)(nrb + n*CG + 2*t) = packbf(nrw[n*CG + 2*t], nrw[n*CG + 2*t + 1]);
  }
}

// ---------- K2 (MFMA): bias[n][h][i][j] per (node, 4-i chunk) ----------
// LAUNCH-BOUNDS LEDGER (hard-won):
//   (256,4) cap128 -> 56-64 VGPR, no spill, PASSES.  [R0/R1/R6/R7: 63-67us]
//   (256,6) cap80  -> 40 VGPR + 34KB/block scratch spill, 122us. [R4]
//   (256,8) cap64  -> numerical corruption absmax~0.11, 2-for-2. [R2,R5]
// STRUCTURE LEDGER:
//   dbuf + deferred-final (R8) -> partial spill (WRITE 26->44MB), 70us. REVERTED.
//   rolling aS prefetch (R7)   -> 63.0us, neutral-positive. KEPT.
// k2 is at its structural floor (~63us) for this decomposition.
__global__ __launch_bounds__(256,4) void k2_bias(
    const long long* __restrict__ eidx, const float* __restrict__ trans,
    const unsigned short* __restrict__ S_all, const unsigned short* __restrict__ nrb,
    const unsigned short* __restrict__ wdTg, const unsigned short* __restrict__ wtTg,
    const unsigned short* __restrict__ bgP, const float* __restrict__ bd,
    float* __restrict__ biasw)
{
  int n = blockIdx.x >> 3, chunk = blockIdx.x & 7;
  int i0 = chunk*4;
  int t = threadIdx.x;
  int wave = t>>6, lane = t&63, q = lane>>4, l15 = lane&15;

  __shared__ __align__(16) unsigned short rbfb[32*72];   // 4.5 KB  [j][r]
  __shared__ __align__(16) unsigned short Xb  [32*136];  // 8.5 KB  [j][c]
  __shared__ __align__(16) float t3s[32][4];
  __shared__ __align__(16) float dsm[4][32];
  __shared__ int srcs[32];

  f32x4 zero4 = {0.f,0.f,0.f,0.f};
  uint4 uz = make_uint4(0,0,0,0);

  // ph0: srcs
  if (t < 32) srcs[t] = (int)eidx[(size_t)n*KKN + t];
  __syncthreads();
  // ph1: t3s gather + per-lane invariant fragments
  if (t < 32){ int s = srcs[t];
    t3s[t][0]=trans[s*3]; t3s[t][1]=trans[s*3+1]; t3s[t][2]=trans[s*3+2]; }
  uint4 wdf[2][2];
  #pragma unroll
  for (int mt=0;mt<2;mt++){
    #pragma unroll
    for (int ks=0;ks<2;ks++)
      wdf[mt][ks] = *(const uint4*)(wdTg + (wave*32+mt*16+l15)*72 + ks*32 + q*8);
  }
  uint4 wtf[4];
  #pragma unroll
  for (int ks=0;ks<4;ks++)
    wtf[ks] = *(const uint4*)(wtTg + (l15&3)*136 + ks*32 + q*8);
  uint4 aBias[2];
  #pragma unroll
  for (int mt=0;mt<2;mt++)
    aBias[mt] = (q == 2) ? *(const uint4*)(bgP + (wave*32+mt*16+l15)*8) : uz;
  uint4 bE[2];
  #pragma unroll
  for (int nt=0;nt<2;nt++){
    int jn = srcs[nt*16 + l15];
    bE[nt] = (q < 2) ? *(const uint4*)(nrb + jn*CG + q*8)
                     : (q == 2 ? make_uint4(0x3F80u,0u,0u,0u) : uz);
  }
  // aS pipeline: issue ii=0's gather now (covered by distance phase + barrier)
  uint4 aS[2], aSn[2];
  {
    int s0 = srcs[i0];
    #pragma unroll
    for (int mt=0;mt<2;mt++)
      aS[mt] = (q < 2) ? *(const uint4*)(S_all + (size_t)s0*2048 + (wave*32+mt*16+l15)*16 + q*8)
                       : aBias[mt];
  }
  __syncthreads();
  // ph2: distances
  if (t < 128){
    int ii=t>>5, j=t&31;
    float dx=t3s[i0+ii][0]-t3s[j][0]+1e-8f;
    float dy=t3s[i0+ii][1]-t3s[j][1]+1e-8f;
    float dz=t3s[i0+ii][2]-t3s[j][2]+1e-8f;
    dsm[ii][j]=sqrtf(dx*dx+dy*dy+dz*dz);
  }
  __syncthreads();

  int jr = t>>3, sl = t&7;
  int c0base = wave*32 + q*4;
  float4 bdv[2];
  #pragma unroll
  for (int mt=0;mt<2;mt++) bdv[mt] = *(const float4*)(bd + c0base + mt*16);

  #pragma unroll 1
  for (int ii=0; ii<4; ii++){
    // dense rbf fill: 8 entries/thread, one aligned b128 write
    {
      float dI = dsm[ii][jr]*RBF_INVSIG;
      float e[8];
      #pragma unroll
      for (int u=0;u<8;u++){
        float x = fmaf((float)(sl*8+u), -RBF_SI, dI);
        e[u] = __expf(-x*x);          // out-of-range terms underflow to exact 0
      }
      *(uint4*)&rbfb[jr*72 + sl*8] = make_uint4(
        packbf(e[0],e[1]), packbf(e[2],e[3]), packbf(e[4],e[5]), packbf(e[6],e[7]));
    }
    // prefetch NEXT ii's aS
    if (ii < 3){
      int s_n = srcs[i0+ii+1];
      #pragma unroll
      for (int mt=0;mt<2;mt++)
        aSn[mt] = (q < 2) ? *(const uint4*)(S_all + (size_t)s_n*2048 + (wave*32+mt*16+l15)*16 + q*8)
                          : aBias[mt];
    }
    __syncthreads();

    f32x4 ga[2][2], da[2][2];
    #pragma unroll
    for(int a=0;a<2;a++){
      #pragma unroll
      for(int b2=0;b2<2;b2++){ ga[a][b2]=zero4; da[a][b2]=zero4; }
    }
    #pragma unroll
    for(int mt=0;mt<2;mt++){
      #pragma unroll
      for(int nt=0;nt<2;nt++)
        ga[mt][nt] = __builtin_amdgcn_mfma_f32_16x16x32_bf16(
          *(const bf16x8*)&aS[mt], *(const bf16x8*)&bE[nt], ga[mt][nt], 0,0,0);
    }
    #pragma unroll
    for(int ks=0;ks<2;ks++){
      bf16x8 bR[2];
      #pragma unroll
      for(int nt=0;nt<2;nt++) bR[nt] = *(const bf16x8*)&rbfb[(nt*16+l15)*72 + ks*32 + q*8];
      #pragma unroll
      for(int mt=0;mt<2;mt++){
        #pragma unroll
        for(int nt=0;nt<2;nt++)
          da[mt][nt] = __builtin_amdgcn_mfma_f32_16x16x32_bf16(
            *(const bf16x8*)&wdf[mt][ks], bR[nt], da[mt][nt], 0,0,0);
      }
    }
    // epilogue: X[j][c] = sigmoid(ga)*(da+bd), bf16  (bg already inside ga)
    #pragma unroll
    for(int mt=0;mt<2;mt++){
      int c0 = c0base + mt*16;
      float4 bv = bdv[mt];
      #pragma unroll
      for(int nt=0;nt<2;nt++){
        float x0 = fastrcp(1.f + __expf(-ga[mt][nt][0]))*(da[mt][nt][0]+bv.x);
        float x1 = fastrcp(1.f + __expf(-ga[mt][nt][1]))*(da[mt][nt][1]+bv.y);
        float x2 = fastrcp(1.f + __expf(-ga[mt][nt][2]))*(da[mt][nt][2]+bv.z);
        float x3 = fastrcp(1.f + __expf(-ga[mt][nt][3]))*(da[mt][nt][3]+bv.w);
        *(uint2*)&Xb[(nt*16+l15)*136 + c0] = make_uint2(packbf(x0,x1), packbf(x2,x3));
      }
    }
    __syncthreads();

    // final: biasT[h][j] = wt[h][:] . X[j][:], waves 0,1 (j-halves)
    if (wave < 2){
      f32x4 bacc = {0.f,0.f,0.f,0.f};
      #pragma unroll
      for(int ks=0;ks<4;ks++){
        bf16x8 bX = *(const bf16x8*)&Xb[(wave*16+l15)*136 + ks*32 + q*8];
        bacc = __builtin_amdgcn_mfma_f32_16x16x32_bf16(*(const bf16x8*)&wtf[ks], bX, bacc, 0,0,0);
      }
      if (q==0){   // rows h=0..3 in quad-0 regs; layout [n][h][i][j]
        int j = wave*16 + l15;
        float* base = biasw + (((size_t)n*4)*32 + (i0+ii))*32 + j;
        base[0] = bacc[0]; base[1024] = bacc[1]; base[2048] = bacc[2]; base[3072] = bacc[3];
      }
    }
    aS[0] = aSn[0]; aS[1] = aSn[1];
  }
}

// ---------- K3: per-node QKV+og (MFMA) + MFMA attention + out-proj (MFMA) ----------
// Round-13: grid reverted to 768 (R12's grid-256 cost +10us — trickle theory
// falsified; TLP matters). New lever: P staging is exactly 32x32 bf16 = 2KB per
// wave (was allotted 4KB) -> smem 48KB -> 40KB -> 4 blocks/CU (was 3) and
// __launch_bounds__(256,4) (VGPR cap 128, same cap k2 runs safely; k3 uses ~68).
// 16 waves/CU vs 12 attacks the latency-bound serial phases. Numerics identical.
__global__ __launch_bounds__(256,4) void k3_attn(
    const unsigned short* __restrict__ zw, const float* __restrict__ biasw,
    const unsigned short* __restrict__ wqkvogT, const unsigned short* __restrict__ woutT,
    const float* __restrict__ bq, const float* __restrict__ bkv, const float* __restrict__ bog,
    const float* __restrict__ bout, float* __restrict__ out)
{
  int n = blockIdx.x, t = threadIdx.x;
  int w = t>>6, lane = t&63, q = lane>>4, l15 = lane&15;

  __shared__ __align__(16) char smem[40960];
  // regions: [0,8K) Q (later y); [8K,16K) K; [16K,24K) VT[128][32]bf16;
  //          [24K,32K) og; [32K,40K) P (2KB wave-private slices)
  f32x4 zero4 = {0.f,0.f,0.f,0.f};

  bf16x8 zfr[2][4];
  #pragma unroll
  for (int nt=0;nt<2;nt++){
    const unsigned short* zr = zw + ((size_t)n*32 + nt*16 + l15)*128;
    #pragma unroll
    for (int ks=0;ks<4;ks++) zfr[nt][ks] = *(const bf16x8*)(zr + ks*32 + q*8);
  }
  // hoisted bias loads (L2-resident from k2) — latency hides under projections
  const float* bb = biasw + (size_t)(n*4 + w)*1024;   // [i][j] for head w
  float bbv[2][4][2];
  #pragma unroll
  for (int mt=0;mt<2;mt++){
    #pragma unroll
    for (int rg=0;rg<4;rg++){
      int i = mt*16 + q*4 + rg;
      bbv[mt][rg][0] = bb[i*32 + l15];
      bbv[mt][rg][1] = bb[i*32 + 16 + l15];
    }
  }
  const float* bseg = (w==0)? bq : (w==1)? bkv : (w==2)? (bkv+128) : bog;

  // ---- QKV+og projections: weight fragments direct from global (L2-hot) ----
  for (int r=0;r<8;r++){
    float4 bv = *(const float4*)(bseg + r*16 + q*4);
    f32x4 acc0 = zero4, acc1 = zero4;
    int cg = w*128 + r*16 + l15;
    const unsigned short* wrow = wqkvogT + cg*128;
    #pragma unroll
    for (int ks=0;ks<4;ks++){
      bf16x8 af = *(const bf16x8*)(wrow + (((ks*4+q) + cg)&15)*8);
      acc0 = __builtin_amdgcn_mfma_f32_16x16x32_bf16(af, zfr[0][ks], acc0, 0,0,0);
      acc1 = __builtin_amdgcn_mfma_f32_16x16x32_bf16(af, zfr[1][ks], acc1, 0,0,0);
    }
    #pragma unroll
    for (int nt=0;nt<2;nt++){
      f32x4 a = nt? acc1 : acc0;
      float v0,v1,v2,v3;
      if (w==3){ v0=sigm(a[0]+bv.x); v1=sigm(a[1]+bv.y); v2=sigm(a[2]+bv.z); v3=sigm(a[3]+bv.w); }
      else     { v0=a[0]+bv.x; v1=a[1]+bv.y; v2=a[2]+bv.z; v3=a[3]+bv.w; }
      int i = nt*16 + l15;
      if (w==2){
        // V transposed: VT[c][j=i], row stride 32 shorts; c = r*16+q*4+rg
        unsigned short* vt = (unsigned short*)(smem + 16384) + (r*16 + q*4)*32 + i;
        unsigned int u01 = packbf(v0,v1), u23 = packbf(v2,v3);
        vt[0]  = (unsigned short)u01;  vt[32] = (unsigned short)(u01>>16);
        vt[64] = (unsigned short)u23;  vt[96] = (unsigned short)(u23>>16);
      } else {
        int blk = ((r*2 + (q>>1)) + i) & 15;
        *(uint2*)(smem + w*8192 + i*256 + blk*16 + (q&1)*8) = make_uint2(packbf(v0,v1), packbf(v2,v3));
      }
    }
  }
  __syncthreads();

  // ---- QK^T via MFMA: wave w = head w; D[i][j] ----
  f32x4 sc4[2][2];
  {
    uint4 aQ[2], bK[2];
    #pragma unroll
    for (int mt=0;mt<2;mt++){
      int row = mt*16 + l15;
      aQ[mt] = *(const uint4*)(smem + row*256 + (((w*4+q) + row)&15)*16);
    }
    #pragma unroll
    for (int nt=0;nt<2;nt++){
      int row = nt*16 + l15;
      bK[nt] = *(const uint4*)(smem + 8192 + row*256 + (((w*4+q) + row)&15)*16);
    }
    #pragma unroll
    for (int mt=0;mt<2;mt++){
      #pragma unroll
      for (int nt=0;nt<2;nt++)
        sc4[mt][nt] = __builtin_amdgcn_mfma_f32_16x16x32_bf16(
          *(const bf16x8*)&aQ[mt], *(const bf16x8*)&bK[nt], zero4, 0,0,0);
    }
  }
  // bias + scale, then row softmax stats (rows i lane-local per (mt,rg))
  float inv_[2][4];
  #pragma unroll
  for (int mt=0;mt<2;mt++){
    #pragma unroll
    for (int rg=0;rg<4;rg++){
      sc4[mt][0][rg] = fmaf(sc4[mt][0][rg], 0.17677669529663687f, bbv[mt][rg][0]);
      sc4[mt][1][rg] = fmaf(sc4[mt][1][rg], 0.17677669529663687f, bbv[mt][rg][1]);
      float m = fmaxf(sc4[mt][0][rg], sc4[mt][1][rg]);
      m = fmaxf(m, __shfl_xor(m,1));
      m = fmaxf(m, __shfl_xor(m,2));
      m = fmaxf(m, __shfl_xor(m,4));
      m = fmaxf(m, __shfl_xor(m,8));
      sc4[mt][0][rg] = __expf(sc4[mt][0][rg] - m);
      sc4[mt][1][rg] = __expf(sc4[mt][1][rg] - m);
      float s = sc4[mt][0][rg] + sc4[mt][1][rg];
      s += __shfl_xor(s,1); s += __shfl_xor(s,2);
      s += __shfl_xor(s,4); s += __shfl_xor(s,8);
      inv_[mt][rg] = fastrcp(s);   // normalization deferred to after PV
    }
  }
  // P (unnormalized) -> wave-private 2KB slice, row-major [i][32 j] bf16
  unsigned short* Pl = (unsigned short*)(smem + 32768 + w*2048);
  #pragma unroll
  for (int mt=0;mt<2;mt++){
    #pragma unroll
    for (int nt=0;nt<2;nt++){
      unsigned int u01 = packbf(sc4[mt][nt][0], sc4[mt][nt][1]);
      unsigned int u23 = packbf(sc4[mt][nt][2], sc4[mt][nt][3]);
      unsigned short* pp = Pl + (mt*16 + q*4)*32 + nt*16 + l15;
      pp[0]  = (unsigned short)u01;  pp[32] = (unsigned short)(u01>>16);
      pp[64] = (unsigned short)u23;  pp[96] = (unsigned short)(u23>>16);
    }
  }
  __syncthreads();   // all Q-region reads complete before y overwrites it

  // ---- PV via MFMA: D2[i][dh] = P[i][:] . VT[w*32+dh][:] ----
  f32x4 ov[2][2];
  {
    uint4 aP[2], bV[2];
    #pragma unroll
    for (int mt=0;mt<2;mt++)
      aP[mt] = *(const uint4*)(Pl + (mt*16 + l15)*32 + q*8);
    #pragma unroll
    for (int nt2=0;nt2<2;nt2++)
      bV[nt2] = *(const uint4*)((unsigned short*)(smem + 16384) + (w*32 + nt2*16 + l15)*32 + q*8);
    #pragma unroll
    for (int mt=0;mt<2;mt++){
      #pragma unroll
      for (int nt2=0;nt2<2;nt2++)
        ov[mt][nt2] = __builtin_amdgcn_mfma_f32_16x16x32_bf16(
          *(const bf16x8*)&aP[mt], *(const bf16x8*)&bV[nt2], zero4, 0,0,0);
    }
  }
  // normalize + gate + write y (bf16, Q region, out-proj fragment layout)
  #pragma unroll
  for (int mt=0;mt<2;mt++){
    #pragma unroll
    for (int nt2=0;nt2<2;nt2++){
      #pragma unroll
      for (int rg=0;rg<4;rg++){
        int i = mt*16 + q*4 + rg;
        int c = w*32 + nt2*16 + l15;
        int off = i*256 + (((c>>3) + i)&15)*16 + (c&7)*2;
        unsigned short gus = *(const unsigned short*)(smem + 24576 + off);
        float g = __uint_as_float(((unsigned int)gus) << 16);
        float yv = ov[mt][nt2][rg] * inv_[mt][rg] * g;
        *(unsigned short*)(smem + off) = (unsigned short)packbf(yv, yv);
      }
    }
  }
  __syncthreads();

  // ---- out-projection: weight fragments direct from global (L2-hot) ----
  bf16x8 yfr[2][4];
  #pragma unroll
  for (int mt=0;mt<2;mt++){
    int row = mt*16 + l15;
    #pragma unroll
    for (int ks=0;ks<4;ks++)
      yfr[mt][ks] = *(const bf16x8*)(smem + row*256 + (((ks*4+q) + row)&15)*16);
  }
  #pragma unroll
  for (int r2=0;r2<2;r2++){
    int c0 = (r2*4 + w)*16;
    int cg2 = c0 + l15;
    const unsigned short* orow = woutT + cg2*128;
    f32x4 oa0 = zero4, oa1 = zero4;
    #pragma unroll
    for (int ks=0;ks<4;ks++){
      bf16x8 bf = *(const bf16x8*)(orow + (((ks*4+q) + cg2)&15)*8);
      oa0 = __builtin_amdgcn_mfma_f32_16x16x32_bf16(yfr[0][ks], bf, oa0, 0,0,0);
      oa1 = __builtin_amdgcn_mfma_f32_16x16x32_bf16(yfr[1][ks], bf, oa1, 0,0,0);
    }
    float bov = bout[cg2];
    #pragma unroll
    for (int mt=0;mt<2;mt++){
      f32x4 oa = mt? oa1 : oa0;
      #pragma unroll
      for (int rg=0; rg<4; rg++){
        int i = mt*16 + q*4 + rg;
        out[((size_t)n*32 + i)*128 + cg2] = oa[rg] + bov;
      }
    }
  }
}

// ---------- launch ----------
extern "C" void kernel_launch(void* const* d_in, const int* in_sizes, int n_in,
                              void* d_out, int out_size, void* d_ws, size_t ws_size,
                              hipStream_t stream)
{
  const float* nf  = (const float*)d_in[0];
  const float* tr  = (const float*)d_in[1];
  const float* ef  = (const float*)d_in[2];
  const long long* ei = (const long long*)d_in[3];
  const float* wl  = (const float*)d_in[4];  const float* bl  = (const float*)d_in[5];
  const float* wr  = (const float*)d_in[6];  const float* br  = (const float*)d_in[7];
  const float* wbg = (const float*)d_in[8];  const float* bbg = (const float*)d_in[9];
  const float* wdi = (const float*)d_in[10]; const float* bdi = (const float*)d_in[11];
  const float* wtb = (const float*)d_in[12];
  const float* lng = (const float*)d_in[13]; const float* lnb = (const float*)d_in[14];
  const float* wq  = (const float*)d_in[15]; const float* bq  = (const float*)d_in[16];
  const float* wkv = (const float*)d_in[17]; const float* bkv = (const float*)d_in[18];
  const float* wo  = (const float*)d_in[19]; const float* bo  = (const float*)d_in[20];
  const float* wog = (const float*)d_in[21]; const float* bog = (const float*)d_in[22];
  float* outp = (float*)d_out;
  float* ws = (float*)d_ws;
  // ws layout (floats). Footprint ends at 5,598,784 floats — proven layout,
  // no growth; bgP lives in the wtTg region's slack (verified R4/R6-R12).
  float* nlw = ws;                                            // [0, 12288)
  float* nrw = ws + 12288;                                    // [12288, 24576)
  float* biasw = ws + 24576;                                  // [24576, 3170304)  [n][h][i][j]
  unsigned short* zw      = (unsigned short*)(ws + 3170304);  // E*CZ bf16
  unsigned short* wqkvogT = (unsigned short*)(ws + 4743168);  // 32768 floats
  unsigned short* woutT   = (unsigned short*)(ws + 4775936);  // 8192 floats
  unsigned short* wdTg    = (unsigned short*)(ws + 4784128);  // 4608 floats
  unsigned short* wtTg    = (unsigned short*)(ws + 4788736);  // 1088 floats; wtT uses [0,544) shorts
  unsigned short* bgPg    = wtTg + 544;                       // wtTg slack (16B-aligned)
  unsigned short* wbPg    = (unsigned short*)(ws + 4789824);  // 16384 floats
  unsigned short* S_all   = (unsigned short*)(ws + 4806208);  // 786432 floats
  unsigned short* nrb     = (unsigned short*)(ws + 5592640);  // 6144 floats -> end 5598784

  // zero nl/nr accumulators (graph-capturable)
  hipMemsetAsync(nlw, 0, 24576*sizeof(float), stream);
  // k1 = LN (1536) + nl/nr GEMM K-split x8 (768) + weight packing (62)
  hipLaunchKernelGGL(k1_pre, dim3(2366), dim3(256), 0, stream,
                     nf, ef, wl, bl, wr, br, lng, lnb, nlw, nrw, zw,
                     wq, wkv, wog, wo, wdi, wtb, wbg, bbg,
                     wqkvogT, woutT, wdTg, wtTg, wbPg, bgPg);
  hipLaunchKernelGGL(k1b_sprep, dim3(768), dim3(256), 0, stream,
                     nlw, nrw, wbPg, S_all, nrb);
  hipLaunchKernelGGL(k2_bias, dim3(6144), dim3(256), 0, stream,
                     ei, tr, S_all, nrb, wdTg, wtTg, bgPg, bdi, biasw);
  // k3: grid 768 (R11-proven best; R12's 256 regressed +10us)
  hipLaunchKernelGGL(k3_attn, dim3(768), dim3(256), 0, stream,
                     zw, biasw, wqkvogT, woutT, bq, bkv, bog, bo, outp);
}

// Round 15
// 187.976 us; speedup vs baseline: 1.0756x; 1.0264x over previous
//
#include <hip/hip_runtime.h>

// Problem constants
#define NN   768
#define KKN  32
#define CS   384
#define CZ   128
#define CG   16
#define NH   4
#define DHD  32
#define NRBF 64
#define EE   (NN*KKN)

#define RBF_STEP    (20.0f/63.0f)
#define RBF_INVSTEP (63.0f/20.0f)
#define RBF_INVSIG  3.2f            // 1/0.3125
#define RBF_SI      (RBF_STEP*RBF_INVSIG)

typedef __attribute__((ext_vector_type(8))) short bf16x8;
typedef __attribute__((ext_vector_type(4))) float f32x4;

// ---------- helpers ----------
__device__ __forceinline__ float bfl(unsigned int u){ return __uint_as_float(u << 16); }
__device__ __forceinline__ float bfh(unsigned int u){ return __uint_as_float(u & 0xFFFF0000u); }
// HW packed f32->bf16 RNE conversion: 1 VALU op
__device__ __forceinline__ unsigned int packbf(float a, float b){
  unsigned int r;
  asm("v_cvt_pk_bf16_f32 %0, %1, %2" : "=v"(r) : "v"(a), "v"(b));
  return r;
}
// raw v_rcp_f32 (~1 ulp) — avoids the IEEE div sequence
__device__ __forceinline__ float fastrcp(float x){
  float r;
  asm("v_rcp_f32 %0, %1" : "=v"(r) : "v"(x));
  return r;
}
__device__ __forceinline__ float sigm(float x){ return fastrcp(1.0f + __expf(-x)); }

// ---------- K1: LN + nl/nr GEMM (K-split x8) + merged one-time weight packing ----------
__global__ __launch_bounds__(256) void k1_pre(
    const float* __restrict__ nf, const float* __restrict__ ef,
    const float* __restrict__ wl, const float* __restrict__ bl,
    const float* __restrict__ wr, const float* __restrict__ br,
    const float* __restrict__ lng, const float* __restrict__ lnb,
    float* __restrict__ nlw, float* __restrict__ nrw,
    unsigned short* __restrict__ zw,
    const float* __restrict__ wq, const float* __restrict__ wkv,
    const float* __restrict__ wog, const float* __restrict__ wout,
    const float* __restrict__ wd, const float* __restrict__ wt,
    const float* __restrict__ wb, const float* __restrict__ bgf,
    unsigned short* __restrict__ wqkvogT, unsigned short* __restrict__ woutT,
    unsigned short* __restrict__ wdT, unsigned short* __restrict__ wtT,
    unsigned short* __restrict__ wbP, unsigned short* __restrict__ bgP)
{
  int b = blockIdx.x, t = threadIdx.x;
  if (b < 1536){
    int rl = t >> 4, l16 = t & 15;
    size_t e = (size_t)b*16 + rl;
    const float4* row = (const float4*)(ef + e*CZ);
    float4 x0 = row[l16*2], x1 = row[l16*2+1];
    float v[8] = {x0.x,x0.y,x0.z,x0.w,x1.x,x1.y,x1.z,x1.w};
    float s = 0.f, q = 0.f;
    #pragma unroll
    for (int u=0;u<8;u++){ s += v[u]; q += v[u]*v[u]; }
    #pragma unroll
    for (int m=1;m<16;m<<=1){ s += __shfl_xor(s,m); q += __shfl_xor(q,m); }
    float mean = s*(1.f/128.f);
    float var  = q*(1.f/128.f) - mean*mean;
    float rs = rsqrtf(var + 1e-5f);
    int c0 = l16*8;
    unsigned int pk[4];
    #pragma unroll
    for (int u=0;u<4;u++){
      float z0 = (v[2*u]  -mean)*rs*lng[c0+2*u]   + lnb[c0+2*u];
      float z1 = (v[2*u+1]-mean)*rs*lng[c0+2*u+1] + lnb[c0+2*u+1];
      pk[u] = packbf(z0,z1);
    }
    ((uint4*)(zw + e*CZ))[l16] = make_uint4(pk[0],pk[1],pk[2],pk[3]);
  } else if (b < 2304){
    int blk2 = b - 1536;           // 0..767
    int seg = blk2 / 96;           // 0..7
    int within = blk2 - seg*96;
    int gid = within*256 + t;      // 0..24575
    int side = (gid >= 12288) ? 1 : 0;
    int idx = gid - side*12288;
    int nd = idx >> 4, c = idx & 15;
    const float* w = side ? wr : wl;
    float acc = (seg==0) ? (side ? br[c] : bl[c]) : 0.f;
    const float* nrow = nf + (size_t)nd*CS;
    int kb = seg*48;
    #pragma unroll 4
    for (int k=kb;k<kb+48;k++) acc += nrow[k]*w[k*CG+c];
    atomicAdd((side? nrw : nlw)+idx, acc);
  } else {
    // ---- weight transpose/pack, ids 0..15683 ----
    int id = (b - 2304)*256 + t;
    float v[8];
    if (id < 8192){
      int c = id & 511, g = id >> 9;
      const float* src; int ld, col;
      if (c < 128){ src = wq; ld = 128; col = c; }
      else if (c < 384){ src = wkv; ld = 256; col = c-128; }
      else { src = wog; ld = 128; col = c-384; }
      #pragma unroll
      for (int j=0;j<8;j++) v[j] = src[(size_t)(g*8+j)*ld + col];
      *(uint4*)(wqkvogT + c*128 + ((g + c)&15)*8) = make_uint4(
        packbf(v[0],v[1]),packbf(v[2],v[3]),packbf(v[4],v[5]),packbf(v[6],v[7]));
    } else if (id < 10240){
      int l = id - 8192; int c = l & 127, g = l >> 7;
      #pragma unroll
      for (int j=0;j<8;j++) v[j] = wout[(size_t)(g*8+j)*128 + c];
      *(uint4*)(woutT + c*128 + ((g + c)&15)*8) = make_uint4(
        packbf(v[0],v[1]),packbf(v[2],v[3]),packbf(v[4],v[5]),packbf(v[6],v[7]));
    } else if (id < 11392){
      int l = id - 10240; int c = l & 127, g = l >> 7;   // g 0..8
      #pragma unroll
      for (int j=0;j<8;j++) v[j] = (g<8) ? wd[(size_t)(g*8+j)*128 + c] : 0.f;
      *(uint4*)(wdT + c*72 + g*8) = make_uint4(
        packbf(v[0],v[1]),packbf(v[2],v[3]),packbf(v[4],v[5]),packbf(v[6],v[7]));
    } else if (id < 11460){
      int l = id - 11392; int h = l / 17, g = l % 17;
      #pragma unroll
      for (int j=0;j<8;j++){ int cc = g*8+j; v[j] = (cc<128)? wt[cc*4 + h] : 0.f; }
      *(uint4*)(wtT + h*136 + g*8) = make_uint4(
        packbf(v[0],v[1]),packbf(v[2],v[3]),packbf(v[4],v[5]),packbf(v[6],v[7]));
    } else if (id < 15556){
      int l2 = id - 11460;           // 0..4095
      int c = l2 >> 5, sl = l2 & 31; // c 0..127, sl 0..31
      int kl0 = sl*8;
      #pragma unroll
      for (int j=0;j<8;j++) v[j] = wb[(size_t)(kl0+j)*128 + c];
      *(uint4*)(wbP + c*256 + kl0) = make_uint4(
        packbf(v[0],v[1]),packbf(v[2],v[3]),packbf(v[4],v[5]),packbf(v[6],v[7]));
    } else if (id < 15684){
      // bgP[c][0..7] = {bf16(bg[c]), 0...} — the k=16 MFMA slot folding bg into ga
      int c = id - 15556;
      *(uint4*)(bgP + c*8) = make_uint4(packbf(bgf[c], 0.f), 0u, 0u, 0u);
    }
  }
}

// ---------- K1b: S_all[s][c*16+l] = nl[s] . wb   (768 blocks) + nr bf16 pack ----------
__global__ __launch_bounds__(256) void k1b_sprep(
    const float* __restrict__ nlw, const float* __restrict__ nrw,
    const unsigned short* __restrict__ wbP,
    unsigned short* __restrict__ S_all, unsigned short* __restrict__ nrb)
{
  int n = blockIdx.x, t = threadIdx.x;
  float e1[16];
  #pragma unroll
  for (int k=0;k<16;k++) e1[k] = nlw[n*CG + k];
  int c = t>>1, l0 = (t&1)*8;
  float S[8];
  #pragma unroll
  for (int u=0;u<8;u++) S[u]=0.f;
  const unsigned short* wrow = wbP + c*256 + l0;
  #pragma unroll 4
  for (int k=0;k<16;k++){
    uint4 wv = *(const uint4*)(wrow + k*16);
    float wf[8] = { bfl(wv.x), bfh(wv.x), bfl(wv.y), bfh(wv.y),
                    bfl(wv.z), bfh(wv.z), bfl(wv.w), bfh(wv.w) };
    float ev = e1[k];
    #pragma unroll
    for (int u=0;u<8;u++) S[u] = fmaf(ev, wf[u], S[u]);
  }
  *(uint4*)(S_all + (size_t)n*2048 + c*16 + l0) = make_uint4(
    packbf(S[0],S[1]), packbf(S[2],S[3]), packbf(S[4],S[5]), packbf(S[6],S[7]));
  if (t < 8){
    *(unsigned int*)(nrb + n*CG + 2*t) = packbf(nrw[n*CG + 2*t], nrw[n*CG + 2*t + 1]);
  }
}

// ---------- K23 (fused bias + attention), one block per node ----------
// Round-15 (R14 resubmit, compile fix: `int w = wave;` — R14 used k2's name
// `wave` in the bias phase but k3's transplanted body references `w`).
// Rationale: k2's FETCH 15.3MB vs ~4MB ideal came from 8 blocks/node each
// re-loading identical per-node fragments (wdf/wtf/bE/srcs/t3s) + biasw 6MB
// HBM round-trip + a launch boundary. Fused block does all 32 ii (was 4x8
// blocks), bias kept in LDS biasF[4][32][32] (16KB f32, same [h][i][j]
// strides), consumed via registers before projections overwrite the region
// (barrier-separated). Bias-loop and attention bodies transplanted VERBATIM.
// LDS: bias phase 34.4K; attention phase 40K. smem 40960.
__global__ __launch_bounds__(256,4) void k23_fused(
    const long long* __restrict__ eidx, const float* __restrict__ trans,
    const unsigned short* __restrict__ S_all, const unsigned short* __restrict__ nrb,
    const unsigned short* __restrict__ wdTg, const unsigned short* __restrict__ wtTg,
    const unsigned short* __restrict__ bgP, const float* __restrict__ bd,
    const unsigned short* __restrict__ zw,
    const unsigned short* __restrict__ wqkvogT, const unsigned short* __restrict__ woutT,
    const float* __restrict__ bq, const float* __restrict__ bkv, const float* __restrict__ bog,
    const float* __restrict__ bout, float* __restrict__ out)
{
  int n = blockIdx.x, t = threadIdx.x;
  int wave = t>>6, lane = t&63, q = lane>>4, l15 = lane&15;
  int w = wave;   // k3-transplant alias (R14's compile failure was this line missing)

  __shared__ __align__(16) char smem[40960];
  // bias phase regions:
  float* biasF          = (float*)smem;                         // [0,16384) f32[4][32][32]
  unsigned short* Xb    = (unsigned short*)(smem + 16384);      // 32*136 sh = 8704 B
  unsigned short* rbfb  = (unsigned short*)(smem + 25088);      // 32*72 sh = 4608 B
  float* dsm            = (float*)(smem + 29696);               // 32*32 f32 = 4096 B
  float* t3s            = (float*)(smem + 33792);               // 32*4 f32 = 512 B
  int*   srcs           = (int*)(smem + 34304);                 // 128 B -> 34432

  f32x4 zero4 = {0.f,0.f,0.f,0.f};
  uint4 uz = make_uint4(0,0,0,0);

  // ================= BIAS PHASE (k2 transplant, ii 0..31) =================
  if (t < 32) srcs[t] = (int)eidx[(size_t)n*KKN + t];
  __syncthreads();
  if (t < 32){ int s = srcs[t];
    t3s[t*4]=trans[s*3]; t3s[t*4+1]=trans[s*3+1]; t3s[t*4+2]=trans[s*3+2]; }
  uint4 wdf[2][2];
  #pragma unroll
  for (int mt=0;mt<2;mt++){
    #pragma unroll
    for (int ks=0;ks<2;ks++)
      wdf[mt][ks] = *(const uint4*)(wdTg + (wave*32+mt*16+l15)*72 + ks*32 + q*8);
  }
  uint4 wtf[4];
  #pragma unroll
  for (int ks=0;ks<4;ks++)
    wtf[ks] = *(const uint4*)(wtTg + (l15&3)*136 + ks*32 + q*8);
  uint4 aBias[2];
  #pragma unroll
  for (int mt=0;mt<2;mt++)
    aBias[mt] = (q == 2) ? *(const uint4*)(bgP + (wave*32+mt*16+l15)*8) : uz;
  uint4 bE[2];
  #pragma unroll
  for (int nt=0;nt<2;nt++){
    int jn = srcs[nt*16 + l15];
    bE[nt] = (q < 2) ? *(const uint4*)(nrb + jn*CG + q*8)
                     : (q == 2 ? make_uint4(0x3F80u,0u,0u,0u) : uz);
  }
  // aS pipeline: ii=0's gather (covered by distance phase + barrier)
  uint4 aS[2], aSn[2];
  {
    int s0 = srcs[0];
    #pragma unroll
    for (int mt=0;mt<2;mt++)
      aS[mt] = (q < 2) ? *(const uint4*)(S_all + (size_t)s0*2048 + (wave*32+mt*16+l15)*16 + q*8)
                       : aBias[mt];
  }
  __syncthreads();
  // distances: all 32x32 pairs, 4 per thread
  #pragma unroll
  for (int u=0;u<4;u++){
    int idx = t + u*256;            // 0..1023
    int di = idx >> 5, j = idx & 31;
    float dx=t3s[di*4]  -t3s[j*4]  +1e-8f;
    float dy=t3s[di*4+1]-t3s[j*4+1]+1e-8f;
    float dz=t3s[di*4+2]-t3s[j*4+2]+1e-8f;
    dsm[di*32+j]=sqrtf(dx*dx+dy*dy+dz*dz);
  }
  __syncthreads();

  int jr = t>>3, sl = t&7;
  int c0base = wave*32 + q*4;
  float4 bdv[2];
  #pragma unroll
  for (int mt=0;mt<2;mt++) bdv[mt] = *(const float4*)(bd + c0base + mt*16);

  #pragma unroll 1
  for (int ii=0; ii<32; ii++){
    // dense rbf fill: 8 entries/thread, one aligned b128 write
    {
      float dI = dsm[ii*32 + jr]*RBF_INVSIG;
      float e[8];
      #pragma unroll
      for (int u=0;u<8;u++){
        float x = fmaf((float)(sl*8+u), -RBF_SI, dI);
        e[u] = __expf(-x*x);          // out-of-range terms underflow to exact 0
      }
      *(uint4*)&rbfb[jr*72 + sl*8] = make_uint4(
        packbf(e[0],e[1]), packbf(e[2],e[3]), packbf(e[4],e[5]), packbf(e[6],e[7]));
    }
    // prefetch NEXT ii's aS
    if (ii < 31){
      int s_n = srcs[ii+1];
      #pragma unroll
      for (int mt=0;mt<2;mt++)
        aSn[mt] = (q < 2) ? *(const uint4*)(S_all + (size_t)s_n*2048 + (wave*32+mt*16+l15)*16 + q*8)
                          : aBias[mt];
    }
    __syncthreads();

    f32x4 ga[2][2], da[2][2];
    #pragma unroll
    for(int a=0;a<2;a++){
      #pragma unroll
      for(int b2=0;b2<2;b2++){ ga[a][b2]=zero4; da[a][b2]=zero4; }
    }
    #pragma unroll
    for(int mt=0;mt<2;mt++){
      #pragma unroll
      for(int nt=0;nt<2;nt++)
        ga[mt][nt] = __builtin_amdgcn_mfma_f32_16x16x32_bf16(
          *(const bf16x8*)&aS[mt], *(const bf16x8*)&bE[nt], ga[mt][nt], 0,0,0);
    }
    #pragma unroll
    for(int ks=0;ks<2;ks++){
      bf16x8 bR[2];
      #pragma unroll
      for(int nt=0;nt<2;nt++) bR[nt] = *(const bf16x8*)&rbfb[(nt*16+l15)*72 + ks*32 + q*8];
      #pragma unroll
      for(int mt=0;mt<2;mt++){
        #pragma unroll
        for(int nt=0;nt<2;nt++)
          da[mt][nt] = __builtin_amdgcn_mfma_f32_16x16x32_bf16(
            *(const bf16x8*)&wdf[mt][ks], bR[nt], da[mt][nt], 0,0,0);
      }
    }
    // epilogue: X[j][c] = sigmoid(ga)*(da+bd), bf16  (bg already inside ga)
    #pragma unroll
    for(int mt=0;mt<2;mt++){
      int c0 = c0base + mt*16;
      float4 bv = bdv[mt];
      #pragma unroll
      for(int nt=0;nt<2;nt++){
        float x0 = fastrcp(1.f + __expf(-ga[mt][nt][0]))*(da[mt][nt][0]+bv.x);
        float x1 = fastrcp(1.f + __expf(-ga[mt][nt][1]))*(da[mt][nt][1]+bv.y);
        float x2 = fastrcp(1.f + __expf(-ga[mt][nt][2]))*(da[mt][nt][2]+bv.z);
        float x3 = fastrcp(1.f + __expf(-ga[mt][nt][3]))*(da[mt][nt][3]+bv.w);
        *(uint2*)&Xb[(nt*16+l15)*136 + c0] = make_uint2(packbf(x0,x1), packbf(x2,x3));
      }
    }
    __syncthreads();

    // final: biasF[h][ii][j] = wt[h][:] . X[j][:], waves 0,1 (j-halves)
    if (wave < 2){
      f32x4 bacc = {0.f,0.f,0.f,0.f};
      #pragma unroll
      for(int ks=0;ks<4;ks++){
        bf16x8 bX = *(const bf16x8*)&Xb[(wave*16+l15)*136 + ks*32 + q*8];
        bacc = __builtin_amdgcn_mfma_f32_16x16x32_bf16(*(const bf16x8*)&wtf[ks], bX, bacc, 0,0,0);
      }
      if (q==0){   // rows h=0..3 in quad-0 regs; layout [h][i][j], h stride 1024
        int j = wave*16 + l15;
        float* base = biasF + ii*32 + j;
        base[0] = bacc[0]; base[1024] = bacc[1]; base[2048] = bacc[2]; base[3072] = bacc[3];
      }
    }
    aS[0] = aSn[0]; aS[1] = aSn[1];
  }
  __syncthreads();

  // ================= ATTENTION PHASE (k3 transplant) =================
  // read bias into registers from LDS (frees [0,16K) for Q/K regions)
  float bbv[2][4][2];
  {
    const float* bbl = biasF + w*1024;   // [i][j] for head w
    #pragma unroll
    for (int mt=0;mt<2;mt++){
      #pragma unroll
      for (int rg=0;rg<4;rg++){
        int i = mt*16 + q*4 + rg;
        bbv[mt][rg][0] = bbl[i*32 + l15];
        bbv[mt][rg][1] = bbl[i*32 + 16 + l15];
      }
    }
  }
  bf16x8 zfr[2][4];
  #pragma unroll
  for (int nt=0;nt<2;nt++){
    const unsigned short* zr = zw + ((size_t)n*32 + nt*16 + l15)*128;
    #pragma unroll
    for (int ks=0;ks<4;ks++) zfr[nt][ks] = *(const bf16x8*)(zr + ks*32 + q*8);
  }
  const float* bseg = (w==0)? bq : (w==1)? bkv : (w==2)? (bkv+128) : bog;
  __syncthreads();   // all biasF reads complete before projections overwrite

  // ---- QKV+og projections: weight fragments direct from global (L2-hot) ----
  for (int r=0;r<8;r++){
    float4 bv = *(const float4*)(bseg + r*16 + q*4);
    f32x4 acc0 = zero4, acc1 = zero4;
    int cg = w*128 + r*16 + l15;
    const unsigned short* wrow = wqkvogT + cg*128;
    #pragma unroll
    for (int ks=0;ks<4;ks++){
      bf16x8 af = *(const bf16x8*)(wrow + (((ks*4+q) + cg)&15)*8);
      acc0 = __builtin_amdgcn_mfma_f32_16x16x32_bf16(af, zfr[0][ks], acc0, 0,0,0);
      acc1 = __builtin_amdgcn_mfma_f32_16x16x32_bf16(af, zfr[1][ks], acc1, 0,0,0);
    }
    #pragma unroll
    for (int nt=0;nt<2;nt++){
      f32x4 a = nt? acc1 : acc0;
      float v0,v1,v2,v3;
      if (w==3){ v0=sigm(a[0]+bv.x); v1=sigm(a[1]+bv.y); v2=sigm(a[2]+bv.z); v3=sigm(a[3]+bv.w); }
      else     { v0=a[0]+bv.x; v1=a[1]+bv.y; v2=a[2]+bv.z; v3=a[3]+bv.w; }
      int i = nt*16 + l15;
      if (w==2){
        // V transposed: VT[c][j=i], row stride 32 shorts; c = r*16+q*4+rg
        unsigned short* vt = (unsigned short*)(smem + 16384) + (r*16 + q*4)*32 + i;
        unsigned int u01 = packbf(v0,v1), u23 = packbf(v2,v3);
        vt[0]  = (unsigned short)u01;  vt[32] = (unsigned short)(u01>>16);
        vt[64] = (unsigned short)u23;  vt[96] = (unsigned short)(u23>>16);
      } else {
        int blk = ((r*2 + (q>>1)) + i) & 15;
        *(uint2*)(smem + w*8192 + i*256 + blk*16 + (q&1)*8) = make_uint2(packbf(v0,v1), packbf(v2,v3));
      }
    }
  }
  __syncthreads();

  // ---- QK^T via MFMA: wave w = head w; D[i][j] ----
  f32x4 sc4[2][2];
  {
    uint4 aQ[2], bK[2];
    #pragma unroll
    for (int mt=0;mt<2;mt++){
      int row = mt*16 + l15;
      aQ[mt] = *(const uint4*)(smem + row*256 + (((w*4+q) + row)&15)*16);
    }
    #pragma unroll
    for (int nt=0;nt<2;nt++){
      int row = nt*16 + l15;
      bK[nt] = *(const uint4*)(smem + 8192 + row*256 + (((w*4+q) + row)&15)*16);
    }
    #pragma unroll
    for (int mt=0;mt<2;mt++){
      #pragma unroll
      for (int nt=0;nt<2;nt++)
        sc4[mt][nt] = __builtin_amdgcn_mfma_f32_16x16x32_bf16(
          *(const bf16x8*)&aQ[mt], *(const bf16x8*)&bK[nt], zero4, 0,0,0);
    }
  }
  // bias + scale, then row softmax stats (rows i lane-local per (mt,rg))
  float inv_[2][4];
  #pragma unroll
  for (int mt=0;mt<2;mt++){
    #pragma unroll
    for (int rg=0;rg<4;rg++){
      sc4[mt][0][rg] = fmaf(sc4[mt][0][rg], 0.17677669529663687f, bbv[mt][rg][0]);
      sc4[mt][1][rg] = fmaf(sc4[mt][1][rg], 0.17677669529663687f, bbv[mt][rg][1]);
      float m = fmaxf(sc4[mt][0][rg], sc4[mt][1][rg]);
      m = fmaxf(m, __shfl_xor(m,1));
      m = fmaxf(m, __shfl_xor(m,2));
      m = fmaxf(m, __shfl_xor(m,4));
      m = fmaxf(m, __shfl_xor(m,8));
      sc4[mt][0][rg] = __expf(sc4[mt][0][rg] - m);
      sc4[mt][1][rg] = __expf(sc4[mt][1][rg] - m);
      float s = sc4[mt][0][rg] + sc4[mt][1][rg];
      s += __shfl_xor(s,1); s += __shfl_xor(s,2);
      s += __shfl_xor(s,4); s += __shfl_xor(s,8);
      inv_[mt][rg] = fastrcp(s);   // normalization deferred to after PV
    }
  }
  // P (unnormalized) -> wave-private 2KB slice, row-major [i][32 j] bf16
  unsigned short* Pl = (unsigned short*)(smem + 32768 + w*2048);
  #pragma unroll
  for (int mt=0;mt<2;mt++){
    #pragma unroll
    for (int nt=0;nt<2;nt++){
      unsigned int u01 = packbf(sc4[mt][nt][0], sc4[mt][nt][1]);
      unsigned int u23 = packbf(sc4[mt][nt][2], sc4[mt][nt][3]);
      unsigned short* pp = Pl + (mt*16 + q*4)*32 + nt*16 + l15;
      pp[0]  = (unsigned short)u01;  pp[32] = (unsigned short)(u01>>16);
      pp[64] = (unsigned short)u23;  pp[96] = (unsigned short)(u23>>16);
    }
  }
  __syncthreads();   // all Q-region reads complete before y overwrites it

  // ---- PV via MFMA: D2[i][dh] = P[i][:] . VT[w*32+dh][:] ----
  f32x4 ov[2][2];
  {
    uint4 aP[2], bV[2];
    #pragma unroll
    for (int mt=0;mt<2;mt++)
      aP[mt] = *(const uint4*)(Pl + (mt*16 + l15)*32 + q*8);
    #pragma unroll
    for (int nt2=0;nt2<2;nt2++)
      bV[nt2] = *(const uint4*)((unsigned short*)(smem + 16384) + (w*32 + nt2*16 + l15)*32 + q*8);
    #pragma unroll
    for (int mt=0;mt<2;mt++){
      #pragma unroll
      for (int nt2=0;nt2<2;nt2++)
        ov[mt][nt2] = __builtin_amdgcn_mfma_f32_16x16x32_bf16(
          *(const bf16x8*)&aP[mt], *(const bf16x8*)&bV[nt2], zero4, 0,0,0);
    }
  }
  // normalize + gate + write y (bf16, Q region, out-proj fragment layout)
  #pragma unroll
  for (int mt=0;mt<2;mt++){
    #pragma unroll
    for (int nt2=0;nt2<2;nt2++){
      #pragma unroll
      for (int rg=0;rg<4;rg++){
        int i = mt*16 + q*4 + rg;
        int c = w*32 + nt2*16 + l15;
        int off = i*256 + (((c>>3) + i)&15)*16 + (c&7)*2;
        unsigned short gus = *(const unsigned short*)(smem + 24576 + off);
        float g = __uint_as_float(((unsigned int)gus) << 16);
        float yv = ov[mt][nt2][rg] * inv_[mt][rg] * g;
        *(unsigned short*)(smem + off) = (unsigned short)packbf(yv, yv);
      }
    }
  }
  __syncthreads();

  // ---- out-projection: weight fragments direct from global (L2-hot) ----
  bf16x8 yfr[2][4];
  #pragma unroll
  for (int mt=0;mt<2;mt++){
    int row = mt*16 + l15;
    #pragma unroll
    for (int ks=0;ks<4;ks++)
      yfr[mt][ks] = *(const bf16x8*)(smem + row*256 + (((ks*4+q) + row)&15)*16);
  }
  #pragma unroll
  for (int r2=0;r2<2;r2++){
    int c0 = (r2*4 + w)*16;
    int cg2 = c0 + l15;
    const unsigned short* orow = woutT + cg2*128;
    f32x4 oa0 = zero4, oa1 = zero4;
    #pragma unroll
    for (int ks=0;ks<4;ks++){
      bf16x8 bf = *(const bf16x8*)(orow + (((ks*4+q) + cg2)&15)*8);
      oa0 = __builtin_amdgcn_mfma_f32_16x16x32_bf16(yfr[0][ks], bf, oa0, 0,0,0);
      oa1 = __builtin_amdgcn_mfma_f32_16x16x32_bf16(yfr[1][ks], bf, oa1, 0,0,0);
    }
    float bov = bout[cg2];
    #pragma unroll
    for (int mt=0;mt<2;mt++){
      f32x4 oa = mt? oa1 : oa0;
      #pragma unroll
      for (int rg=0; rg<4; rg++){
        int i = mt*16 + q*4 + rg;
        out[((size_t)n*32 + i)*128 + cg2] = oa[rg] + bov;
      }
    }
  }
}

// ---------- launch ----------
extern "C" void kernel_launch(void* const* d_in, const int* in_sizes, int n_in,
                              void* d_out, int out_size, void* d_ws, size_t ws_size,
                              hipStream_t stream)
{
  const float* nf  = (const float*)d_in[0];
  const float* tr  = (const float*)d_in[1];
  const float* ef  = (const float*)d_in[2];
  const long long* ei = (const long long*)d_in[3];
  const float* wl  = (const float*)d_in[4];  const float* bl  = (const float*)d_in[5];
  const float* wr  = (const float*)d_in[6];  const float* br  = (const float*)d_in[7];
  const float* wbg = (const float*)d_in[8];  const float* bbg = (const float*)d_in[9];
  const float* wdi = (const float*)d_in[10]; const float* bdi = (const float*)d_in[11];
  const float* wtb = (const float*)d_in[12];
  const float* lng = (const float*)d_in[13]; const float* lnb = (const float*)d_in[14];
  const float* wq  = (const float*)d_in[15]; const float* bq  = (const float*)d_in[16];
  const float* wkv = (const float*)d_in[17]; const float* bkv = (const float*)d_in[18];
  const float* wo  = (const float*)d_in[19]; const float* bo  = (const float*)d_in[20];
  const float* wog = (const float*)d_in[21]; const float* bog = (const float*)d_in[22];
  float* outp = (float*)d_out;
  float* ws = (float*)d_ws;
  // ws layout (floats). Footprint ends at 5,598,784 floats — proven layout,
  // no growth; biasw slot now unused (bias lives in LDS); bgP in wtTg slack.
  float* nlw = ws;                                            // [0, 12288)
  float* nrw = ws + 12288;                                    // [12288, 24576)
  unsigned short* zw      = (unsigned short*)(ws + 3170304);  // E*CZ bf16
  unsigned short* wqkvogT = (unsigned short*)(ws + 4743168);  // 32768 floats
  unsigned short* woutT   = (unsigned short*)(ws + 4775936);  // 8192 floats
  unsigned short* wdTg    = (unsigned short*)(ws + 4784128);  // 4608 floats
  unsigned short* wtTg    = (unsigned short*)(ws + 4788736);  // 1088 floats; wtT uses [0,544) shorts
  unsigned short* bgPg    = wtTg + 544;                       // wtTg slack (16B-aligned)
  unsigned short* wbPg    = (unsigned short*)(ws + 4789824);  // 16384 floats
  unsigned short* S_all   = (unsigned short*)(ws + 4806208);  // 786432 floats
  unsigned short* nrb     = (unsigned short*)(ws + 5592640);  // 6144 floats -> end 5598784

  // zero nl/nr accumulators (graph-capturable)
  hipMemsetAsync(nlw, 0, 24576*sizeof(float), stream);
  // k1 = LN (1536) + nl/nr GEMM K-split x8 (768) + weight packing (62)
  hipLaunchKernelGGL(k1_pre, dim3(2366), dim3(256), 0, stream,
                     nf, ef, wl, bl, wr, br, lng, lnb, nlw, nrw, zw,
                     wq, wkv, wog, wo, wdi, wtb, wbg, bbg,
                     wqkvogT, woutT, wdTg, wtTg, wbPg, bgPg);
  hipLaunchKernelGGL(k1b_sprep, dim3(768), dim3(256), 0, stream,
                     nlw, nrw, wbPg, S_all, nrb);
  // fused bias+attention: one block per node
  hipLaunchKernelGGL(k23_fused, dim3(768), dim3(256), 0, stream,
                     ei, tr, S_all, nrb, wdTg, wtTg, bgPg, bdi,
                     zw, wqkvogT, woutT, bq, bkv, bog, bo, outp);
}